// Round 14
// baseline (100.773 us; speedup 1.0000x reference)
//
#include <hip/hip_runtime.h>
#include <hip/hip_fp16.h>

// B=4, S=512, D=256, UNITS=128. out: [B,S,D] fp32.
#define SEQ 512
#define DIM 256
#define UN  128
#define BSZ 2048                       // B*S
#define CSC 2.8853900817779268f        // 2*log2(e)
#define EVS 2176
#define VTS 2176
#define PS  640

typedef _Float16 half8 __attribute__((ext_vector_type(8)));
typedef float   float4v __attribute__((ext_vector_type(4)));
struct h4s { __half2 a, b; };          // 8B = 4 f16

static __device__ __forceinline__ unsigned short f2bf(float x) {  // RNE, x>0 finite
  unsigned u = __float_as_uint(x);
  u += 0x7FFF + ((u >> 16) & 1);
  return (unsigned short)(u >> 16);
}
static __device__ __forceinline__ float bf2f(unsigned short s) {
  return __uint_as_float((unsigned)s << 16);
}
static __device__ __forceinline__ float rdlane(float v, int k) {
  return __int_as_float(__builtin_amdgcn_readlane(__float_as_int(v), k));
}

// ---- proj (r13 verbatim): Eq fp32 [BSZ][UN]; Ev bf16^T [UN x EVS]; Vt f16^T [DIM x VTS]
__global__ __launch_bounds__(256) void proj_kernel(
    const float* __restrict__ values, const float* __restrict__ Wq,
    const float* __restrict__ Wv, float* __restrict__ Eq,
    unsigned short* __restrict__ Ev, _Float16* __restrict__ Vt) {
  __shared__ float vsm[4 * DIM];
  const int t = threadIdx.x;
  const int r0 = blockIdx.x * 4;
  {
    const int row = t >> 6, c4 = (t & 63) * 4;
    const float4 v = *(const float4*)(values + (r0 + row) * DIM + c4);
    *(float4*)&vsm[row * DIM + c4] = v;
  }
  __syncthreads();
  {
    h4s o;
    o.a = __floats2half2_rn(vsm[0 * DIM + t], vsm[1 * DIM + t]);
    o.b = __floats2half2_rn(vsm[2 * DIM + t], vsm[3 * DIM + t]);
    *(h4s*)(Vt + (size_t)t * VTS + r0) = o;
  }
  const int half = t >> 7, u = t & 127;
  const float* __restrict__ W = half ? Wv : Wq;
  float acc[4] = {0.f, 0.f, 0.f, 0.f};
  for (int d = 0; d < DIM; d += 4) {
    const float w0 = W[(d + 0) * UN + u], w1 = W[(d + 1) * UN + u];
    const float w2 = W[(d + 2) * UN + u], w3 = W[(d + 3) * UN + u];
#pragma unroll
    for (int k = 0; k < 4; ++k) {
      const float4 v = *(const float4*)&vsm[k * DIM + d];
      acc[k] = fmaf(v.x, w0, acc[k]);
      acc[k] = fmaf(v.y, w1, acc[k]);
      acc[k] = fmaf(v.z, w2, acc[k]);
      acc[k] = fmaf(v.w, w3, acc[k]);
    }
  }
  if (!half) {
#pragma unroll
    for (int k = 0; k < 4; ++k)
      Eq[(r0 + k) * UN + u] = __builtin_amdgcn_exp2f(acc[k] * CSC);
  } else {
    ushort4 o;
    o.x = f2bf(__builtin_amdgcn_exp2f(acc[0] * CSC));
    o.y = f2bf(__builtin_amdgcn_exp2f(acc[1] * CSC));
    o.z = f2bf(__builtin_amdgcn_exp2f(acc[2] * CSC));
    o.w = f2bf(__builtin_amdgcn_exp2f(acc[3] * CSC));
    *(ushort4*)(Ev + (size_t)u * EVS + r0) = o;   // 8B aligned
  }
}

// ---- score2: 2048 blocks, 8 blocks/CU (32 waves/CU). Block = (pair, jhalf).
// jhalf=0: dual rows {p,511-p}, j<256. jhalf=1: hi row only, j in [256,512).
// Each wave owns a 32-u strip; raw sdot (f32) partials combined in LDS -> Sd.
__global__ __launch_bounds__(256, 8) void score2_kernel(
    const float* __restrict__ Eq, const unsigned short* __restrict__ Ev,
    const float* __restrict__ Vw, float* __restrict__ Sd) {
  __shared__ float pl[4 * 256];
  __shared__ float ph[4 * 256];
  const int t = threadIdx.x, lane = t & 63, w = t >> 6;
  const int x = blockIdx.x;
  const int pairIdx = x >> 1, jhalf = x & 1;
  const int b = pairIdx >> 8, p = pairIdx & 255;
  const int bS = b * SEQ;
  const int i = p, ihi = SEQ - 1 - p;
  const int u0 = w << 5;                       // this wave's 32-u strip
  const int jb = lane << 2;                    // lane <-> j-quad (256 j per half)

  // 32 loop-uniforms preloaded into lanes 0..31 (dup 32..63)
  const int lk = lane & 31;
  const float qlv = Eq[(size_t)(bS + i) * UN + u0 + lk];
  const float qhv = Eq[(size_t)(bS + ihi) * UN + u0 + lk];
  const float wvv = Vw[u0 + lk];

  const unsigned short* __restrict__ evp =
      Ev + (size_t)u0 * EVS + bS + (jhalf << 8) + jb;
#define LDE(K) (*(const ushort4*)(evp + (size_t)(K) * EVS))
  if (jhalf == 0) {                            // dual rows
    float h0=0.f,h1=0.f,h2=0.f,h3=0.f,l0=0.f,l1=0.f,l2=0.f,l3=0.f;
    ushort4 e[4] = {LDE(0), LDE(1), LDE(2), LDE(3)};
#pragma clang loop unroll(disable)
    for (int k = 0; k < 32; k += 4) {
#pragma unroll
      for (int r = 0; r < 4; ++r) {
        // overshoot <= u0+35 <= 131 < 136 rows alloc'd: valid
        const ushort4 n = LDE(k + 4 + r);
        const float qh = rdlane(qhv, k + r);
        const float ql = rdlane(qlv, k + r);
        const float ww = rdlane(wvv, k + r);
        const float f0 = bf2f(e[r].x), f1 = bf2f(e[r].y);
        const float f2 = bf2f(e[r].z), f3 = bf2f(e[r].w);
        const float a0 = fmaf(ql, f0, 1.f), b0 = fmaf(qh, f0, 1.f);
        const float a1 = fmaf(ql, f1, 1.f), b1 = fmaf(qh, f1, 1.f);
        const float a2 = fmaf(ql, f2, 1.f), b2 = fmaf(qh, f2, 1.f);
        const float a3 = fmaf(ql, f3, 1.f), b3 = fmaf(qh, f3, 1.f);
        const float s0 = ww * __builtin_amdgcn_rcpf(a0 * b0);
        const float s1 = ww * __builtin_amdgcn_rcpf(a1 * b1);
        const float s2 = ww * __builtin_amdgcn_rcpf(a2 * b2);
        const float s3 = ww * __builtin_amdgcn_rcpf(a3 * b3);
        l0 = fmaf(s0, b0, l0); h0 = fmaf(s0, a0, h0);
        l1 = fmaf(s1, b1, l1); h1 = fmaf(s1, a1, h1);
        l2 = fmaf(s2, b2, l2); h2 = fmaf(s2, a2, h2);
        l3 = fmaf(s3, b3, l3); h3 = fmaf(s3, a3, h3);
        e[r] = n;
      }
    }
    *(float4*)&pl[(w << 8) + jb] = make_float4(l0, l1, l2, l3);
    *(float4*)&ph[(w << 8) + jb] = make_float4(h0, h1, h2, h3);
    __syncthreads();
    const float lo = pl[t] + pl[256 + t] + pl[512 + t] + pl[768 + t];
    const float hi = ph[t] + ph[256 + t] + ph[512 + t] + ph[768 + t];
    Sd[(size_t)(bS + i) * SEQ + t]   = lo;     // cols [0,256)
    Sd[(size_t)(bS + ihi) * SEQ + t] = hi;
  } else {                                     // hi row only, cols [256,512)
    float h0=0.f,h1=0.f,h2=0.f,h3=0.f;
    ushort4 e[4] = {LDE(0), LDE(1), LDE(2), LDE(3)};
#pragma clang loop unroll(disable)
    for (int k = 0; k < 32; k += 4) {
#pragma unroll
      for (int r = 0; r < 4; ++r) {
        const ushort4 n = LDE(k + 4 + r);
        const float qh = rdlane(qhv, k + r);
        const float ww = rdlane(wvv, k + r);
        const float f0 = bf2f(e[r].x), f1 = bf2f(e[r].y);
        const float f2 = bf2f(e[r].z), f3 = bf2f(e[r].w);
        const float a  = fmaf(qh, f0, 1.f), bb = fmaf(qh, f1, 1.f);
        const float c  = fmaf(qh, f2, 1.f), d  = fmaf(qh, f3, 1.f);
        const float sA = ww * __builtin_amdgcn_rcpf(a * bb);
        const float sB = ww * __builtin_amdgcn_rcpf(c * d);
        h0 = fmaf(sA, bb, h0); h1 = fmaf(sA, a, h1);
        h2 = fmaf(sB, d,  h2); h3 = fmaf(sB, c, h3);
        e[r] = n;
      }
    }
    *(float4*)&ph[(w << 8) + jb] = make_float4(h0, h1, h2, h3);
    __syncthreads();
    const float hi = ph[t] + ph[256 + t] + ph[512 + t] + ph[768 + t];
    Sd[(size_t)(bS + ihi) * SEQ + 256 + t] = hi;
  }
#undef LDE
}

// ---- smax: one wave per row; exact causal mask (Sd cols > row range are
// garbage/unwritten -> masked before min/exp). Writes normalized P f16 w/ zeros.
__global__ __launch_bounds__(256) void smax_kernel(
    const float* __restrict__ Sd, _Float16* __restrict__ P) {
  const int t = threadIdx.x, lane = t & 63, w = t >> 6;
  const int r = blockIdx.x * 4 + w;            // global row
  const int i = r & (SEQ - 1);                 // causal length
  const float* __restrict__ row = Sd + (size_t)r * SEQ;
  const int c0 = lane * 8;
  const float4 sA = *(const float4*)(row + c0);
  const float4 sB = *(const float4*)(row + c0 + 4);
  float v[8] = {sA.x, sA.y, sA.z, sA.w, sB.x, sB.y, sB.z, sB.w};
  float m = 1e30f;                             // min sdot == max score
#pragma unroll
  for (int c = 0; c < 8; ++c) if (c0 + c <= i) m = fminf(m, v[c]);
#pragma unroll
  for (int o = 32; o; o >>= 1) m = fminf(m, __shfl_xor(m, o));
  float pr[8]; float sum = 0.f;
#pragma unroll
  for (int c = 0; c < 8; ++c) {
    pr[c] = (c0 + c <= i) ? __builtin_amdgcn_exp2f((m - v[c]) * CSC) : 0.f;
    sum += pr[c];
  }
#pragma unroll
  for (int o = 32; o; o >>= 1) sum += __shfl_xor(sum, o);
  const float inv = __builtin_amdgcn_rcpf(sum);
  half8 o8;
#pragma unroll
  for (int c = 0; c < 8; ++c) o8[c] = (_Float16)(pr[c] * inv);
  *(half8*)(P + (size_t)r * PS + c0) = o8;     // 16B aligned
}

// ---- ctx: out = P @ values via MFMA 16x16x32 f16 (r13, unchanged).
__global__ __launch_bounds__(256) void ctx_kernel(
    const _Float16* __restrict__ P, const _Float16* __restrict__ Vt,
    float* __restrict__ out) {
  const int t = threadIdx.x, lane = t & 63, g = t >> 6;
  const int x = blockIdx.x;
  const int b = x >> 7, ri = (x >> 2) & 31, cg = x & 3;
  const int bS = b * SEQ;
  const int d0 = cg * 64 + g * 16;
  const int m = lane & 15, q = lane >> 4;
  const int Kmax = 16 * ri + 16;               // causal cap for this row tile

  const _Float16* __restrict__ pA = P  + (size_t)(bS + 16 * ri + m) * PS + q * 8;
  const _Float16* __restrict__ pB = Vt + (size_t)(d0 + m) * VTS + bS + q * 8;
  float4v acc = {0.f, 0.f, 0.f, 0.f};
  for (int k0 = 0; k0 < Kmax; k0 += 32) {
    const half8 a  = *(const half8*)(pA + k0);
    const half8 bv = *(const half8*)(pB + k0);
    acc = __builtin_amdgcn_mfma_f32_16x16x32_f16(a, bv, acc, 0, 0, 0);
  }
  float* __restrict__ o = out + (size_t)(bS + 16 * ri + q * 4) * DIM + d0 + m;
#pragma unroll
  for (int r = 0; r < 4; ++r) o[(size_t)r * DIM] = acc[r];
}

extern "C" void kernel_launch(void* const* d_in, const int* in_sizes, int n_in,
                              void* d_out, int out_size, void* d_ws, size_t ws_size,
                              hipStream_t stream) {
  const float* values = (const float*)d_in[0];
  const float* Wq     = (const float*)d_in[1];
  const float* Wv     = (const float*)d_in[2];
  const float* Vw     = (const float*)d_in[3];
  float* out = (float*)d_out;
  float* Eq = (float*)d_ws;                                       // [BSZ][UN] 1 MB
  unsigned short* Ev = (unsigned short*)(Eq + (size_t)BSZ * UN);  // 136 x EVS bf16
  _Float16* Vt = (_Float16*)(Ev + (size_t)136 * EVS);             // DIM x VTS f16
  _Float16* P  = Vt + (size_t)DIM * VTS;                          // BSZ x PS f16
  float* Sd    = (float*)(P + (size_t)BSZ * PS);                  // BSZ x SEQ f32 raw sdot
  proj_kernel<<<dim3(BSZ / 4), 256, 0, stream>>>(values, Wq, Wv, Eq, Ev, Vt);
  score2_kernel<<<dim3(2048), 256, 0, stream>>>(Eq, Ev, Vw, Sd);
  smax_kernel<<<dim3(512), 256, 0, stream>>>(Sd, P);
  ctx_kernel<<<dim3(512), 256, 0, stream>>>(P, Vt, out);
}

// Round 15
// 97.852 us; speedup vs baseline: 1.0299x; 1.0299x over previous
//
#include <hip/hip_runtime.h>
#include <hip/hip_fp16.h>

// B=4, S=512, D=256, UNITS=128. out: [B,S,D] fp32.
#define SEQ 512
#define DIM 256
#define UN  128
#define BSZ 2048                       // B*S
#define CSC 2.8853900817779268f        // 2*log2(e)
#define EVS 2176
#define VTS 2176
#define PS  640

typedef _Float16 half8 __attribute__((ext_vector_type(8)));
typedef float   float4v __attribute__((ext_vector_type(4)));
typedef unsigned short us8 __attribute__((ext_vector_type(8)));  // 16B -> dwordx4
struct h4s { __half2 a, b; };          // 8B = 4 f16

static __device__ __forceinline__ unsigned short f2bf(float x) {  // RNE, x>0 finite
  unsigned u = __float_as_uint(x);
  u += 0x7FFF + ((u >> 16) & 1);
  return (unsigned short)(u >> 16);
}
static __device__ __forceinline__ float bf2f(unsigned short s) {
  return __uint_as_float((unsigned)s << 16);
}
static __device__ __forceinline__ float rdlane(float v, int k) {
  return __int_as_float(__builtin_amdgcn_readlane(__float_as_int(v), k));
}

// ---- proj (r13 verbatim): Eq fp32 [BSZ][UN]; Ev bf16^T [UN x EVS]; Vt f16^T [DIM x VTS]
__global__ __launch_bounds__(256) void proj_kernel(
    const float* __restrict__ values, const float* __restrict__ Wq,
    const float* __restrict__ Wv, float* __restrict__ Eq,
    unsigned short* __restrict__ Ev, _Float16* __restrict__ Vt) {
  __shared__ float vsm[4 * DIM];
  const int t = threadIdx.x;
  const int r0 = blockIdx.x * 4;
  {
    const int row = t >> 6, c4 = (t & 63) * 4;
    const float4 v = *(const float4*)(values + (r0 + row) * DIM + c4);
    *(float4*)&vsm[row * DIM + c4] = v;
  }
  __syncthreads();
  {
    h4s o;
    o.a = __floats2half2_rn(vsm[0 * DIM + t], vsm[1 * DIM + t]);
    o.b = __floats2half2_rn(vsm[2 * DIM + t], vsm[3 * DIM + t]);
    *(h4s*)(Vt + (size_t)t * VTS + r0) = o;
  }
  const int half = t >> 7, u = t & 127;
  const float* __restrict__ W = half ? Wv : Wq;
  float acc[4] = {0.f, 0.f, 0.f, 0.f};
  for (int d = 0; d < DIM; d += 4) {
    const float w0 = W[(d + 0) * UN + u], w1 = W[(d + 1) * UN + u];
    const float w2 = W[(d + 2) * UN + u], w3 = W[(d + 3) * UN + u];
#pragma unroll
    for (int k = 0; k < 4; ++k) {
      const float4 v = *(const float4*)&vsm[k * DIM + d];
      acc[k] = fmaf(v.x, w0, acc[k]);
      acc[k] = fmaf(v.y, w1, acc[k]);
      acc[k] = fmaf(v.z, w2, acc[k]);
      acc[k] = fmaf(v.w, w3, acc[k]);
    }
  }
  if (!half) {
#pragma unroll
    for (int k = 0; k < 4; ++k)
      Eq[(r0 + k) * UN + u] = __builtin_amdgcn_exp2f(acc[k] * CSC);
  } else {
    ushort4 o;
    o.x = f2bf(__builtin_amdgcn_exp2f(acc[0] * CSC));
    o.y = f2bf(__builtin_amdgcn_exp2f(acc[1] * CSC));
    o.z = f2bf(__builtin_amdgcn_exp2f(acc[2] * CSC));
    o.w = f2bf(__builtin_amdgcn_exp2f(acc[3] * CSC));
    *(ushort4*)(Ev + (size_t)u * EVS + r0) = o;   // 8B aligned
  }
}

// ---- score: block = (b, pair p), rows {p, 511-p}. Phase A: lane l owns j=8l..8l+7
// via ONE 16B ushort8 load per (u,lane) — the whole 512-col row per wave-instr.
// Waves = u-quarters. Lanes<32 (j<256) keep both rows; lanes>=32 hi only.
// Load instrs per block: 4x32 = 128 (r13: 272) at identical bytes & eval count.
__global__ __launch_bounds__(256, 4) void score_kernel(
    const float* __restrict__ Eq, const unsigned short* __restrict__ Ev,
    const float* __restrict__ Vw, _Float16* __restrict__ P) {
  __shared__ float shi4[4 * SEQ];   // [u-quarter][512] hi-row sdot partials
  __shared__ float slo4[4 * 256];   // [u-quarter][256] lo-row sdot partials
  __shared__ float invs[2];

  const int t = threadIdx.x, lane = t & 63, w = t >> 6;
  const int x = blockIdx.x;
  const int b = x >> 8, p = x & 255;
  const int bS = b * SEQ;
  const int i = p;                  // low row: j in [0, i], i <= 255
  const int ihi = SEQ - 1 - p;      // high row: j in [0, jhi], jhi >= 256
  const int jhi = ihi;
  const int u0 = w << 5;            // this wave's u-quarter
  const int lk = lane & 31;

  // 32 loop-uniforms preloaded into lanes (dup halves)
  const float qlv = Eq[(size_t)(bS + i) * UN + u0 + lk];
  const float qhv = Eq[(size_t)(bS + ihi) * UN + u0 + lk];
  const float wvv = Vw[u0 + lk];

  // ---- phase A ----
  {
    const unsigned short* __restrict__ evp = Ev + (size_t)u0 * EVS + bS + lane * 8;
#define LDE(K) (*(const us8*)(evp + (size_t)(K) * EVS))
    float h[8], l[8];
#pragma unroll
    for (int c = 0; c < 8; ++c) { h[c] = 0.f; l[c] = 0.f; }
    us8 e0 = LDE(0), e1 = LDE(1);
#pragma clang loop unroll(disable)
    for (int k = 0; k < 32; k += 2) {
      {  // step 0 (consume e0)
        const us8 n = LDE(k + 2);   // overshoot <= row u0+33 <= 129 < 136: valid
        const float qh = rdlane(qhv, k), ql = rdlane(qlv, k), ww = rdlane(wvv, k);
#pragma unroll
        for (int c = 0; c < 8; ++c) {
          const float f = bf2f(e0[c]);
          const float aa = fmaf(ql, f, 1.f);     // lo denom
          const float bb = fmaf(qh, f, 1.f);     // hi denom
          const float s = ww * __builtin_amdgcn_rcpf(aa * bb);
          l[c] = fmaf(s, bb, l[c]);              // ww/aa
          h[c] = fmaf(s, aa, h[c]);              // ww/bb
        }
        e0 = n;
      }
      {  // step 1 (consume e1)
        const us8 n = LDE(k + 3);
        const float qh = rdlane(qhv, k + 1), ql = rdlane(qlv, k + 1), ww = rdlane(wvv, k + 1);
#pragma unroll
        for (int c = 0; c < 8; ++c) {
          const float f = bf2f(e1[c]);
          const float aa = fmaf(ql, f, 1.f);
          const float bb = fmaf(qh, f, 1.f);
          const float s = ww * __builtin_amdgcn_rcpf(aa * bb);
          l[c] = fmaf(s, bb, l[c]);
          h[c] = fmaf(s, aa, h[c]);
        }
        e1 = n;
      }
    }
#undef LDE
    float* __restrict__ hw = &shi4[(w << 9) + lane * 8];
    *(float4*)(hw + 0) = make_float4(h[0], h[1], h[2], h[3]);
    *(float4*)(hw + 4) = make_float4(h[4], h[5], h[6], h[7]);
    if (lane < 32) {                 // j < 256: lo row valid
      float* __restrict__ lw = &slo4[(w << 8) + lane * 8];
      *(float4*)(lw + 0) = make_float4(l[0], l[1], l[2], l[3]);
      *(float4*)(lw + 4) = make_float4(l[4], l[5], l[6], l[7]);
    }
  }
  __syncthreads();

  // ---- phase B: softmax; wave0 -> low row, wave1 -> high row (4-partial sums) ----
  {
    if (w == 0) {
      float m = 1e30f;                           // min sdot == max score
      for (int j = lane; j <= i; j += 64)
        m = fminf(m, slo4[j] + slo4[256 + j] + slo4[512 + j] + slo4[768 + j]);
#pragma unroll
      for (int o = 32; o; o >>= 1) m = fminf(m, __shfl_xor(m, o));
      float sum = 0.f;
      for (int j = lane; j <= i; j += 64) {
        const float s = slo4[j] + slo4[256 + j] + slo4[512 + j] + slo4[768 + j];
        const float pr = __builtin_amdgcn_exp2f((m - s) * CSC);
        slo4[j] = pr;                            // w0 slice only; safe in-place
        sum += pr;
      }
#pragma unroll
      for (int o = 32; o; o >>= 1) sum += __shfl_xor(sum, o);
      if (lane == 0) invs[0] = __builtin_amdgcn_rcpf(sum);
    } else if (w == 1) {
      float m = 1e30f;
      for (int j = lane; j <= jhi; j += 64)
        m = fminf(m, shi4[j] + shi4[512 + j] + shi4[1024 + j] + shi4[1536 + j]);
#pragma unroll
      for (int o = 32; o; o >>= 1) m = fminf(m, __shfl_xor(m, o));
      float sum = 0.f;
      for (int j = lane; j <= jhi; j += 64) {
        const float s = shi4[j] + shi4[512 + j] + shi4[1024 + j] + shi4[1536 + j];
        const float pr = __builtin_amdgcn_exp2f((m - s) * CSC);
        shi4[j] = pr;
        sum += pr;
      }
#pragma unroll
      for (int o = 32; o; o >>= 1) sum += __shfl_xor(sum, o);
      if (lane == 0) invs[1] = __builtin_amdgcn_rcpf(sum);
    }
  }
  __syncthreads();

  // ---- epilogue: normalized f16 P (stride PS) with zeros in masked slots ----
  {
    const float invLo = invs[0], invHi = invs[1];
    const int t2 = t + 256;
    const float pLo = (t <= i) ? slo4[t] * invLo : 0.f;          // lo cols [0,256)
    const float pHa = shi4[t] * invHi;                            // t <= 255 <= jhi
    const float pHb = (t2 <= jhi) ? shi4[t2] * invHi : 0.f;       // hi cols [256,512)
    P[(size_t)(bS + i) * PS + t]    = (_Float16)pLo;
    P[(size_t)(bS + ihi) * PS + t]  = (_Float16)pHa;
    P[(size_t)(bS + ihi) * PS + t2] = (_Float16)pHb;
  }
}

// ---- ctx: out = P @ values via MFMA 16x16x32 f16 (r13, unchanged).
__global__ __launch_bounds__(256) void ctx_kernel(
    const _Float16* __restrict__ P, const _Float16* __restrict__ Vt,
    float* __restrict__ out) {
  const int t = threadIdx.x, lane = t & 63, g = t >> 6;
  const int x = blockIdx.x;
  const int b = x >> 7, ri = (x >> 2) & 31, cg = x & 3;
  const int bS = b * SEQ;
  const int d0 = cg * 64 + g * 16;
  const int m = lane & 15, q = lane >> 4;
  const int Kmax = 16 * ri + 16;                 // causal cap for this row tile

  const _Float16* __restrict__ pA = P  + (size_t)(bS + 16 * ri + m) * PS + q * 8;
  const _Float16* __restrict__ pB = Vt + (size_t)(d0 + m) * VTS + bS + q * 8;
  float4v acc = {0.f, 0.f, 0.f, 0.f};
  for (int k0 = 0; k0 < Kmax; k0 += 32) {
    const half8 a  = *(const half8*)(pA + k0);
    const half8 bv = *(const half8*)(pB + k0);
    acc = __builtin_amdgcn_mfma_f32_16x16x32_f16(a, bv, acc, 0, 0, 0);
  }
  float* __restrict__ o = out + (size_t)(bS + 16 * ri + q * 4) * DIM + d0 + m;
#pragma unroll
  for (int r = 0; r < 4; ++r) o[(size_t)r * DIM] = acc[r];
}

extern "C" void kernel_launch(void* const* d_in, const int* in_sizes, int n_in,
                              void* d_out, int out_size, void* d_ws, size_t ws_size,
                              hipStream_t stream) {
  const float* values = (const float*)d_in[0];
  const float* Wq     = (const float*)d_in[1];
  const float* Wv     = (const float*)d_in[2];
  const float* Vw     = (const float*)d_in[3];
  float* out = (float*)d_out;
  float* Eq = (float*)d_ws;                                       // [BSZ][UN] 1 MB
  unsigned short* Ev = (unsigned short*)(Eq + (size_t)BSZ * UN);  // 136 x EVS bf16
  _Float16* Vt = (_Float16*)(Ev + (size_t)136 * EVS);             // DIM x VTS f16
  _Float16* P  = Vt + (size_t)DIM * VTS;                          // BSZ x PS f16
  proj_kernel<<<dim3(BSZ / 4), 256, 0, stream>>>(values, Wq, Wv, Eq, Ev, Vt);
  score_kernel<<<dim3(4 * 256), 256, 0, stream>>>(Eq, Ev, Vw, P);
  ctx_kernel<<<dim3(512), 256, 0, stream>>>(P, Vt, out);
}